// Round 5
// baseline (79.618 us; speedup 1.0000x reference)
//
#include <hip/hip_runtime.h>
#include <math.h>

#define N_POINTS   262144
#define NUM_FREQS  10
#define NUM_VOXELS 512
#define RSTRIDE_H  72                        // halfs per (voxel,row): 64 + 8 pad
                                             // = 144 B = 36 dw; 36 mod 32 = 4 ->
                                             // 8 bank-rotation classes, balanced
#define ROW_HALFS  (NUM_VOXELS * RSTRIDE_H)  // 36864 halfs = 73728 B per row image
#define ROW_F4     (ROW_HALFS / 8)           // 4608 uint4 per row image

// R14: row-split 3-phase double-buffered pipeline.
// Post-mortem R13 (kernel ~26 us): the voxel-half split issued every gather
// and dot TWICE at half lane occupancy (masked `if (v>>8)==h`), and staging
// was load->ds_write with per-iter vmcnt(0), unhidden at 1 block/CU.
// Fix: split by OUTPUT ROW. One row-image (all 512 voxels x 64 packed cols,
// stride 72 halfs) = 73728 B; TWO fit in LDS (147456 B) -> 3-phase pipeline:
//   stage(row0); bar
//   phase rw: issue loads(row rw+1) -> compute row rw (8 ds_read_b128 +
//             32 fdot2, FULL wave, no mask) -> ds_write(row rw+1) -> bar
// Gather: 24 full-wave b128/pt total (vs 48 half-wave).  Staging latency
// hides under compute (T14 issue-early/write-late).  R11 lesson holds: no
// global atomics; R12 lesson holds: pack once into ws (LDS-exact image).
//
// ws: 3 row images, image rw at half-offset rw*36864; per (v,rw): 64 packed
// cols (pad col 3 = 0, matching enc pair (x2,0)) + 8 zero tail halfs.

typedef _Float16 half2v __attribute__((ext_vector_type(2)));

__device__ __forceinline__ half2v u2h(unsigned int u) {
    union { unsigned int u; half2v h; } c; c.u = u; return c.h;
}

__device__ __forceinline__ float dot2acc(half2v a, half2v b, float acc) {
#if __has_builtin(__builtin_amdgcn_fdot2)
    return __builtin_amdgcn_fdot2(a, b, acc, false);
#else
    return acc + (float)a[0] * (float)b[0] + (float)a[1] * (float)b[1];
#endif
}

__device__ __forceinline__ half2v pkrtz(float a, float b) {
#if __has_builtin(__builtin_amdgcn_cvt_pkrtz)
    auto r = __builtin_amdgcn_cvt_pkrtz(a, b);   // v_cvt_pkrtz_f16_f32
    union { decltype(r) r_; half2v h; } c; c.r_ = r; return c.h;
#else
    half2v h; h[0] = (_Float16)a; h[1] = (_Float16)b; return h;
#endif
}

// ---------------------------------------------------------------------------
// pack_w: fp32 W (1536x63) -> ws fp16 row images.  13824 threads, 8 halfs
// (one float4 store) each.  54 blocks x 256 = 13824 exact.
// ---------------------------------------------------------------------------
__global__ __launch_bounds__(256) void pack_w(
    const float* __restrict__ W, _Float16* __restrict__ Wp)
{
    const int g   = blockIdx.x * 256 + threadIdx.x;   // [0, 13824)
    const int v   = g / 27;                           // voxel 0..511
    const int rem = g - v * 27;
    const int rw  = rem / 9;                          // row 0..2
    const int gg  = rem - rw * 9;                     // uint4 group 0..8
    union { _Float16 h[8]; float4 f4; } u;
    #pragma unroll
    for (int j = 0; j < 8; ++j) {
        const int pc = gg * 8 + j;                    // packed col 0..71
        float val = 0.0f;
        if (pc < 64 && pc != 3) {
            const int wc = pc - (pc >= 4);            // W col 0..62
            val = W[v * 189 + rw * 63 + wc];
        }
        u.h[j] = (_Float16)val;                       // RNE for weights
    }
    _Float16* dst = Wp + (size_t)rw * ROW_HALFS + v * RSTRIDE_H + gg * 8;
    *reinterpret_cast<float4*>(dst) = u.f4;           // 16B-aligned
}

// ---------------------------------------------------------------------------
// Main: 256 blocks x 1024 threads, one point per thread, 1 block/CU.
// LDS 147456 B = 2 row-image buffers.
// ---------------------------------------------------------------------------
__global__ __launch_bounds__(1024) void voxlin_rows(
    const float* __restrict__ X,
    const _Float16* __restrict__ Wp,
    const int* __restrict__ row_ids,
    const int* __restrict__ voxel_ids,
    float* __restrict__ out)
{
    __shared__ uint4 buf[2][ROW_F4];                  // 2 x 73728 B

    const int t = threadIdx.x;
    const int i = blockIdx.x * 1024 + t;

    // ---- stage row 0 (issue loads first; posenc hides the latency) ----
    const uint4* __restrict__ wsrc = (const uint4*)Wp;
    uint4 tmp[5];
    #pragma unroll
    for (int k = 0; k < 5; ++k) {
        const int idx = k * 1024 + t;
        if (idx < ROW_F4) tmp[k] = wsrc[idx];         // row 0
    }

    const int   v   = voxel_ids[i];
    const int   rid = row_ids[i];
    const float x0  = X[3*i + 0];
    const float x1  = X[3*i + 1];
    const float x2  = X[3*i + 2];

    // ---- posenc once (double-angle recurrence), packed to half2 ----
    half2v eh[32];
    eh[0] = pkrtz(x0, x1);
    eh[1] = pkrtz(x2, 0.0f);                 // pairs with zero pad col 3
    {
        float s0, c0, s1, c1, s2, c2;
        __sincosf(x0, &s0, &c0);
        __sincosf(x1, &s1, &c1);
        __sincosf(x2, &s2, &c2);
        #pragma unroll
        for (int f = 0; f < NUM_FREQS; ++f) {
            const int b = 2 + 3 * f;         // [s0 s1 | s2 c0 | c1 c2]
            eh[b + 0] = pkrtz(s0, s1);
            eh[b + 1] = pkrtz(s2, c0);
            eh[b + 2] = pkrtz(c1, c2);
            if (f < NUM_FREQS - 1) {
                const float ns0 = 2.0f*s0*c0, nc0 = c0*c0 - s0*s0;
                const float ns1 = 2.0f*s1*c1, nc1 = c1*c1 - s1*s1;
                const float ns2 = 2.0f*s2*c2, nc2 = c2*c2 - s2*s2;
                s0 = ns0; c0 = nc0; s1 = ns1; c1 = nc1; s2 = ns2; c2 = nc2;
            }
        }
    }

    // ---- write row 0 into buf[0] ----
    #pragma unroll
    for (int k = 0; k < 5; ++k) {
        const int idx = k * 1024 + t;
        if (idx < ROW_F4) buf[0][idx] = tmp[k];
    }
    __syncthreads();

    // ---- 3-phase pipeline: compute row rw from buf[rw&1], prefetch rw+1 ----
    float res[3];
    #pragma unroll
    for (int rw = 0; rw < 3; ++rw) {
        if (rw < 2) {                                 // issue next-row loads
            const uint4* __restrict__ src = (const uint4*)Wp + (rw + 1) * ROW_F4;
            #pragma unroll
            for (int k = 0; k < 5; ++k) {
                const int idx = k * 1024 + t;
                if (idx < ROW_F4) tmp[k] = src[idx];
            }
        }

        // compute: 8 ds_read_b128 + 32 fdot2, full wave, no masking
        const uint4* __restrict__ wb = &buf[rw & 1][v * 9];
        float a = 0.0f;
        #pragma unroll
        for (int k = 0; k < 8; ++k) {
            const uint4 q = wb[k];
            a = dot2acc(u2h(q.x), eh[4*k + 0], a);
            a = dot2acc(u2h(q.y), eh[4*k + 1], a);
            a = dot2acc(u2h(q.z), eh[4*k + 2], a);
            a = dot2acc(u2h(q.w), eh[4*k + 3], a);
        }
        res[rw] = a;

        if (rw < 2) {                                 // write-late, then bar
            #pragma unroll
            for (int k = 0; k < 5; ++k) {
                const int idx = k * 1024 + t;
                if (idx < ROW_F4) buf[(rw + 1) & 1][idx] = tmp[k];
            }
            __syncthreads();
        }
    }

    // ---- write-out in original row order (row_ids coalesced) ----
    out[3*rid + 0] = res[0];
    out[3*rid + 1] = res[1];
    out[3*rid + 2] = res[2];
}

// ---------------------------------------------------------------------------
// Fallback (R1 kernel) if ws too small for the 216 KB packed image.
// ---------------------------------------------------------------------------
__global__ __launch_bounds__(256) void voxlin_fallback(
    const float* __restrict__ X, const float* __restrict__ W,
    const int* __restrict__ row_ids, const int* __restrict__ voxel_ids,
    float* __restrict__ out)
{
    const int i = blockIdx.x * 256 + threadIdx.x;
    if (i >= N_POINTS) return;
    const float x0 = X[3*i], x1 = X[3*i+1], x2 = X[3*i+2];
    const int v = voxel_ids[i];
    const float* __restrict__ w0 = W + v * 189;
    const float* __restrict__ w1 = w0 + 63;
    const float* __restrict__ w2 = w0 + 126;
    float a0 = x0*w0[0] + x1*w0[1] + x2*w0[2];
    float a1 = x0*w1[0] + x1*w1[1] + x2*w1[2];
    float a2 = x0*w2[0] + x1*w2[1] + x2*w2[2];
    float s0, c0, s1, c1, s2, c2;
    __sincosf(x0, &s0, &c0); __sincosf(x1, &s1, &c1); __sincosf(x2, &s2, &c2);
    #pragma unroll
    for (int f = 0; f < NUM_FREQS; ++f) {
        const int b = 3 + 6*f;
        a0 += s0*w0[b] + s1*w0[b+1] + s2*w0[b+2] + c0*w0[b+3] + c1*w0[b+4] + c2*w0[b+5];
        a1 += s0*w1[b] + s1*w1[b+1] + s2*w1[b+2] + c0*w1[b+3] + c1*w1[b+4] + c2*w1[b+5];
        a2 += s0*w2[b] + s1*w2[b+1] + s2*w2[b+2] + c0*w2[b+3] + c1*w2[b+4] + c2*w2[b+5];
        if (f < NUM_FREQS - 1) {
            const float ns0 = 2.0f*s0*c0, nc0 = c0*c0 - s0*s0;
            const float ns1 = 2.0f*s1*c1, nc1 = c1*c1 - s1*s1;
            const float ns2 = 2.0f*s2*c2, nc2 = c2*c2 - s2*s2;
            s0 = ns0; c0 = nc0; s1 = ns1; c1 = nc1; s2 = ns2; c2 = nc2;
        }
    }
    const int rr = row_ids[i];
    out[3*rr] = a0; out[3*rr+1] = a1; out[3*rr+2] = a2;
}

// ---------------------------------------------------------------------------
extern "C" void kernel_launch(void* const* d_in, const int* in_sizes, int n_in,
                              void* d_out, int out_size, void* d_ws, size_t ws_size,
                              hipStream_t stream) {
    const float* X         = (const float*)d_in[0];
    const float* W         = (const float*)d_in[1];
    const int*   row_ids   = (const int*)d_in[2];
    const int*   voxel_ids = (const int*)d_in[3];
    float*       out       = (float*)d_out;

    const size_t need = (size_t)3 * ROW_HALFS * sizeof(_Float16); // 221184 B

    if (ws_size >= need) {
        _Float16* Wp = (_Float16*)d_ws;
        pack_w<<<54, 256, 0, stream>>>(W, Wp);
        voxlin_rows<<<N_POINTS / 1024, 1024, 0, stream>>>(X, Wp, row_ids,
                                                          voxel_ids, out);
    } else {
        voxlin_fallback<<<(N_POINTS + 255) / 256, 256, 0, stream>>>(
            X, W, row_ids, voxel_ids, out);
    }
}

// Round 6
// 69.593 us; speedup vs baseline: 1.1440x; 1.1440x over previous
//
#include <hip/hip_runtime.h>
#include <math.h>

#define N_POINTS   262144
#define NUM_FREQS  10
#define NUM_VOXELS 512
#define HALF_VOX   256
#define VSTRIDE    200     // halfs per voxel (400 B = 100 dw; start bank-group
                           // = v mod 8 -> balanced for random v)
#define HALF_HALFS (HALF_VOX * VSTRIDE)       // 51200 halfs = 102400 B
#define HALF_F4    (HALF_HALFS / 8)           // 6400 uint4 per half-table
#define CHUNKS     (HALF_HALFS * 2 / 1024)    // 100 x 1024 B wave-chunks

// R15 = R13 (best-known, 69.55) + zero-register async staging.
// Post-mortem R14: reg-staged prefetch (tmp[5] live across posenc+compute)
// at 1024-thread launch_bounds -> VGPR pressure/spill + 3 barrier drains =
// -9 us.  Reverted to R13's half-split.  R13's residual was stall time at
// the two staging barriers: load->vmcnt->ds_write serial per iter, all 16
// waves waiting on the slowest stager, 1 block/CU so nothing overlaps.
// Fix: __builtin_amdgcn_global_load_lds width=16 (compiler never auto-emits
// it): ~6 async DMA issues per wave, zero dest VGPRs, one vmcnt drain at the
// barrier instead of 6 serial round-trips; phase-0 latency hides under
// posenc.  Staging is linear (wave-uniform LDS base + lane*16) -- exactly
// the instruction's addressing model.
// R11 lesson holds: no global atomics.  R12 lesson holds: pack once into ws
// (LDS-exact image, pads pre-zeroed); also fixed R13's pack_w OOB (51200
// threads for 25600 groups read past W).
//
// ws: [0, 204800) fp16 table, half h at h*102400 B; per voxel 200 halfs =
// 3 rows x 64 packed cols (pad col 3 = 0, matching enc pair (x2,0)) + 8 tail.

typedef _Float16 half2v __attribute__((ext_vector_type(2)));

__device__ __forceinline__ half2v u2h(unsigned int u) {
    union { unsigned int u; half2v h; } c; c.u = u; return c.h;
}

__device__ __forceinline__ float dot2acc(half2v a, half2v b, float acc) {
#if __has_builtin(__builtin_amdgcn_fdot2)
    return __builtin_amdgcn_fdot2(a, b, acc, false);
#else
    return acc + (float)a[0] * (float)b[0] + (float)a[1] * (float)b[1];
#endif
}

__device__ __forceinline__ half2v pkrtz(float a, float b) {
#if __has_builtin(__builtin_amdgcn_cvt_pkrtz)
    auto r = __builtin_amdgcn_cvt_pkrtz(a, b);   // v_cvt_pkrtz_f16_f32
    union { decltype(r) r_; half2v h; } c; c.r_ = r; return c.h;
#else
    half2v h; h[0] = (_Float16)a; h[1] = (_Float16)b; return h;
#endif
}

// ---------------------------------------------------------------------------
// pack_w: fp32 W (1536x63) -> ws fp16 LDS image.  25600 groups of 4 halfs,
// one per thread (float2 store).  25 blocks x 1024 exact.
// ---------------------------------------------------------------------------
__global__ __launch_bounds__(1024) void pack_w(
    const float* __restrict__ W, _Float16* __restrict__ Wp)
{
    const int g  = blockIdx.x * 1024 + threadIdx.x;   // [0, 25600)
    const int v  = g / 50;                            // voxel 0..511
    const int p0 = (g - v * 50) * 4;                  // packed pos 0,4,..,196
    union { _Float16 h[4]; float2 f2; } u;
    #pragma unroll
    for (int j = 0; j < 4; ++j) {
        const int p = p0 + j;                         // 0..199
        float val = 0.0f;
        if (p < 192) {
            const int row = p >> 6, col = p & 63;
            if (col != 3) {
                const int wc = col - (col >= 4);      // W col 0..62
                val = W[v * 189 + row * 63 + wc];
            }
        }
        u.h[j] = (_Float16)val;                       // RNE for weights
    }
    _Float16* dst = Wp + (size_t)(v >> 8) * HALF_HALFS
                       + (size_t)(v & 255) * VSTRIDE + p0;
    *reinterpret_cast<float2*>(dst) = u.f2;           // 8B-aligned
}

// ---------------------------------------------------------------------------
// Async stage: half-table (102400 B) -> LDS, wave-chunked, zero dest VGPRs.
// Chunk c (1024 B): wave (c mod 16); lane l copies bytes [c*1024+16l, +16).
// ---------------------------------------------------------------------------
__device__ __forceinline__ void stage_async(
    const _Float16* __restrict__ WpHalf, _Float16* lw, int t)
{
#if __has_builtin(__builtin_amdgcn_global_load_lds)
    const int lane = t & 63;
    const int w    = t >> 6;                          // wave 0..15
    const char* src = (const char*)WpHalf + lane * 16;
    char*       dst = (char*)lw;
    #pragma unroll
    for (int c = w; c < 2 * CHUNKS / 2; c += 16) {    // c = w, w+16, ... < 100
        __builtin_amdgcn_global_load_lds(
            (const __attribute__((address_space(1))) void*)(src + (size_t)c * 1024),
            (__attribute__((address_space(3))) void*)(dst + (size_t)c * 1024),
            16, 0, 0);
    }
#else
    const float4* __restrict__ s4 = (const float4*)WpHalf;
    float4* d4 = (float4*)lw;
    for (int j = t; j < HALF_F4; j += 1024) d4[j] = s4[j];
#endif
}

// ---------------------------------------------------------------------------
// Main: 256 blocks x 1024 threads, one point per thread, 1 block/CU.
//   issue stage(half0) -> posenc (hides DMA latency) -> bar ->
//   masked compute half0 -> bar -> issue stage(half1) -> bar ->
//   masked compute half1 -> coalesced out
// ---------------------------------------------------------------------------
__global__ __launch_bounds__(1024) void voxlin_lds(
    const float* __restrict__ X,
    const _Float16* __restrict__ Wp,
    const int* __restrict__ row_ids,
    const int* __restrict__ voxel_ids,
    float* __restrict__ out)
{
    __shared__ float4 lwv[HALF_F4];                   // 102400 B
    _Float16* const lw = (_Float16*)lwv;

    const int t = threadIdx.x;
    const int i = blockIdx.x * 1024 + t;

    // ---- issue half-0 DMA first: latency hides under loads + posenc ----
    stage_async(Wp, lw, t);

    const int   v  = voxel_ids[i];
    const float x0 = X[3*i + 0];
    const float x1 = X[3*i + 1];
    const float x2 = X[3*i + 2];
    const int   r  = row_ids[i];

    // ---- posenc once (double-angle recurrence), packed to half2 ----
    half2v eh[32];
    eh[0] = pkrtz(x0, x1);
    eh[1] = pkrtz(x2, 0.0f);                 // pairs with zero pad col 3
    {
        float s0, c0, s1, c1, s2, c2;
        __sincosf(x0, &s0, &c0);
        __sincosf(x1, &s1, &c1);
        __sincosf(x2, &s2, &c2);
        #pragma unroll
        for (int f = 0; f < NUM_FREQS; ++f) {
            const int b = 2 + 3 * f;         // [s0 s1 | s2 c0 | c1 c2]
            eh[b + 0] = pkrtz(s0, s1);
            eh[b + 1] = pkrtz(s2, c0);
            eh[b + 2] = pkrtz(c1, c2);
            if (f < NUM_FREQS - 1) {
                const float ns0 = 2.0f*s0*c0, nc0 = c0*c0 - s0*s0;
                const float ns1 = 2.0f*s1*c1, nc1 = c1*c1 - s1*s1;
                const float ns2 = 2.0f*s2*c2, nc2 = c2*c2 - s2*s2;
                s0 = ns0; c0 = nc0; s1 = ns1; c1 = nc1; s2 = ns2; c2 = nc2;
            }
        }
    }

    float a0 = 0.0f, a1 = 0.0f, a2 = 0.0f;

    #pragma unroll
    for (int h = 0; h < 2; ++h) {
        if (h == 1) {
            __syncthreads();                 // all compute-0 done before restage
            stage_async(Wp + HALF_HALFS, lw, t);
        }
        __syncthreads();                     // drains vmcnt -> LDS table ready

        // ---- masked compute: lanes whose voxel is in this half ----
        if ((v >> 8) == h) {
            const uint4* __restrict__ wb =
                (const uint4*)lw + (v & (HALF_VOX - 1)) * (VSTRIDE / 8);
            float acc[3];
            #pragma unroll
            for (int rr = 0; rr < 3; ++rr) {
                float a = 0.0f;
                #pragma unroll
                for (int k = 0; k < 8; ++k) {
                    const uint4 q = wb[rr * 8 + k];
                    a = dot2acc(u2h(q.x), eh[4*k + 0], a);
                    a = dot2acc(u2h(q.y), eh[4*k + 1], a);
                    a = dot2acc(u2h(q.z), eh[4*k + 2], a);
                    a = dot2acc(u2h(q.w), eh[4*k + 3], a);
                }
                acc[rr] = a;
            }
            a0 = acc[0]; a1 = acc[1]; a2 = acc[2];
        }
    }

    // ---- full-wave write-out in original row order ----
    out[3*r + 0] = a0;
    out[3*r + 1] = a1;
    out[3*r + 2] = a2;
}

// ---------------------------------------------------------------------------
// Fallback (R1 kernel) if ws too small for the 200 KB packed image.
// ---------------------------------------------------------------------------
__global__ __launch_bounds__(256) void voxlin_fallback(
    const float* __restrict__ X, const float* __restrict__ W,
    const int* __restrict__ row_ids, const int* __restrict__ voxel_ids,
    float* __restrict__ out)
{
    const int i = blockIdx.x * 256 + threadIdx.x;
    if (i >= N_POINTS) return;
    const float x0 = X[3*i], x1 = X[3*i+1], x2 = X[3*i+2];
    const int v = voxel_ids[i];
    const float* __restrict__ w0 = W + v * 189;
    const float* __restrict__ w1 = w0 + 63;
    const float* __restrict__ w2 = w0 + 126;
    float a0 = x0*w0[0] + x1*w0[1] + x2*w0[2];
    float a1 = x0*w1[0] + x1*w1[1] + x2*w1[2];
    float a2 = x0*w2[0] + x1*w2[1] + x2*w2[2];
    float s0, c0, s1, c1, s2, c2;
    __sincosf(x0, &s0, &c0); __sincosf(x1, &s1, &c1); __sincosf(x2, &s2, &c2);
    #pragma unroll
    for (int f = 0; f < NUM_FREQS; ++f) {
        const int b = 3 + 6*f;
        a0 += s0*w0[b] + s1*w0[b+1] + s2*w0[b+2] + c0*w0[b+3] + c1*w0[b+4] + c2*w0[b+5];
        a1 += s0*w1[b] + s1*w1[b+1] + s2*w1[b+2] + c0*w1[b+3] + c1*w1[b+4] + c2*w1[b+5];
        a2 += s0*w2[b] + s1*w2[b+1] + s2*w2[b+2] + c0*w2[b+3] + c1*w2[b+4] + c2*w2[b+5];
        if (f < NUM_FREQS - 1) {
            const float ns0 = 2.0f*s0*c0, nc0 = c0*c0 - s0*s0;
            const float ns1 = 2.0f*s1*c1, nc1 = c1*c1 - s1*s1;
            const float ns2 = 2.0f*s2*c2, nc2 = c2*c2 - s2*s2;
            s0 = ns0; c0 = nc0; s1 = ns1; c1 = nc1; s2 = ns2; c2 = nc2;
        }
    }
    const int rr = row_ids[i];
    out[3*rr] = a0; out[3*rr+1] = a1; out[3*rr+2] = a2;
}

// ---------------------------------------------------------------------------
extern "C" void kernel_launch(void* const* d_in, const int* in_sizes, int n_in,
                              void* d_out, int out_size, void* d_ws, size_t ws_size,
                              hipStream_t stream) {
    const float* X         = (const float*)d_in[0];
    const float* W         = (const float*)d_in[1];
    const int*   row_ids   = (const int*)d_in[2];
    const int*   voxel_ids = (const int*)d_in[3];
    float*       out       = (float*)d_out;

    const size_t need = (size_t)2 * HALF_HALFS * sizeof(_Float16); // 204800 B

    if (ws_size >= need) {
        _Float16* Wp = (_Float16*)d_ws;
        pack_w<<<25, 1024, 0, stream>>>(W, Wp);
        voxlin_lds<<<N_POINTS / 1024, 1024, 0, stream>>>(X, Wp, row_ids,
                                                         voxel_ids, out);
    } else {
        voxlin_fallback<<<(N_POINTS + 255) / 256, 256, 0, stream>>>(
            X, W, row_ids, voxel_ids, out);
    }
}

// Round 7
// 69.362 us; speedup vs baseline: 1.1479x; 1.0033x over previous
//
#include <hip/hip_runtime.h>
#include <math.h>

#define N_POINTS   262144
#define NUM_FREQS  10
#define NUM_VOXELS 512
#define HALF_VOX   256
#define VSTRIDE    200     // halfs per voxel (400 B = 100 dw; start bank-group
                           // = v mod 8 -> balanced for random v)
#define HALF_HALFS (HALF_VOX * VSTRIDE)       // 51200 halfs = 102400 B
#define HALF_F4    (HALF_HALFS / 8)           // 6400 uint4 per half-table
#define CHUNKS     (HALF_HALFS * 2 / 1024)    // 100 x 1024 B wave-chunks

// R16 = R15 + 2-way partition (halve gather/dot issue) + pack_w regrid.
// Post-mortem R15: async staging exactly null vs R13 (69.59 vs 69.55) ->
// staging stalls were NOT the residual.  R9/R10/R13/R15 all 69.5-73 despite
// different gather sources/barriers/staging => remaining candidates:
// (H1) the masked two-phase compute issues every gather+dot TWICE at ~half
// lane occupancy; (H2) dispatch/gap overhead.  This round: partition points
// by voxel-half into LDS slots (ballot+popc prefix, no atomics), so phase h
// computes a CONTIGUOUS slot range at full occupancy (execz skips the rest),
// and results unpermute through pts (R9-proven: thread keeps mypos + r in
// regs).  pack_w regridded 25x1024 -> 100x256 (was a 25-CU straggler).
// R11 lesson: no global atomics.  R12 lesson: pack once into ws.
//
// ws: [0, 204800) fp16 table, half h at h*102400 B; per voxel 200 halfs =
// 3 rows x 64 packed cols (pad col 3 = 0, matching enc pair (x2,0)) + 8 tail.

typedef _Float16 half2v __attribute__((ext_vector_type(2)));

__device__ __forceinline__ half2v u2h(unsigned int u) {
    union { unsigned int u; half2v h; } c; c.u = u; return c.h;
}

__device__ __forceinline__ float dot2acc(half2v a, half2v b, float acc) {
#if __has_builtin(__builtin_amdgcn_fdot2)
    return __builtin_amdgcn_fdot2(a, b, acc, false);
#else
    return acc + (float)a[0] * (float)b[0] + (float)a[1] * (float)b[1];
#endif
}

__device__ __forceinline__ half2v pkrtz(float a, float b) {
#if __has_builtin(__builtin_amdgcn_cvt_pkrtz)
    auto r = __builtin_amdgcn_cvt_pkrtz(a, b);   // v_cvt_pkrtz_f16_f32
    union { decltype(r) r_; half2v h; } c; c.r_ = r; return c.h;
#else
    half2v h; h[0] = (_Float16)a; h[1] = (_Float16)b; return h;
#endif
}

// ---------------------------------------------------------------------------
// pack_w: fp32 W (1536x63) -> ws fp16 LDS image.  25600 groups of 4 halfs,
// one per thread (float2 store).  100 blocks x 256 exact (wide grid: the
// old 25x1024 ran on only 25 CUs).
// ---------------------------------------------------------------------------
__global__ __launch_bounds__(256) void pack_w(
    const float* __restrict__ W, _Float16* __restrict__ Wp)
{
    const int g  = blockIdx.x * 256 + threadIdx.x;    // [0, 25600)
    const int v  = g / 50;                            // voxel 0..511
    const int p0 = (g - v * 50) * 4;                  // packed pos 0,4,..,196
    union { _Float16 h[4]; float2 f2; } u;
    #pragma unroll
    for (int j = 0; j < 4; ++j) {
        const int p = p0 + j;                         // 0..199
        float val = 0.0f;
        if (p < 192) {
            const int row = p >> 6, col = p & 63;
            if (col != 3) {
                const int wc = col - (col >= 4);      // W col 0..62
                val = W[v * 189 + row * 63 + wc];
            }
        }
        u.h[j] = (_Float16)val;                       // RNE for weights
    }
    _Float16* dst = Wp + (size_t)(v >> 8) * HALF_HALFS
                       + (size_t)(v & 255) * VSTRIDE + p0;
    *reinterpret_cast<float2*>(dst) = u.f2;           // 8B-aligned
}

// ---------------------------------------------------------------------------
// Async stage: half-table (102400 B) -> LDS, wave-chunked, zero dest VGPRs.
// Chunk c (1024 B): wave (c mod 16); lane l copies bytes [c*1024+16l, +16).
// __syncthreads() drains vmcnt -> table valid after the following barrier.
// ---------------------------------------------------------------------------
__device__ __forceinline__ void stage_async(
    const _Float16* __restrict__ WpHalf, _Float16* lw, int t)
{
#if __has_builtin(__builtin_amdgcn_global_load_lds)
    const int lane = t & 63;
    const int w    = t >> 6;                          // wave 0..15
    const char* src = (const char*)WpHalf + lane * 16;
    char*       dst = (char*)lw;
    #pragma unroll
    for (int c = w; c < CHUNKS; c += 16) {            // c = w, w+16, ... < 100
        __builtin_amdgcn_global_load_lds(
            (const __attribute__((address_space(1))) void*)(src + (size_t)c * 1024),
            (__attribute__((address_space(3))) void*)(dst + (size_t)c * 1024),
            16, 0, 0);
    }
#else
    const float4* __restrict__ s4 = (const float4*)WpHalf;
    float4* d4 = (float4*)lw;
    for (int j = t; j < HALF_F4; j += 1024) d4[j] = s4[j];
#endif
}

// ---------------------------------------------------------------------------
// Main: 256 blocks x 1024 threads, one point per thread, 1 block/CU.
//   issue stage(half0) -> partition points by voxel-half into pts[] ->
//   posenc(slot point) -> compute slots [0,n0) on half0 (full-occupancy
//   waves; others execz-skip) -> restage -> compute slots [n0,1024) on
//   half1 -> unpermute through pts -> coalesced out.
// LDS: table 100 KB + pts 16 KB + wcnt = 116.1 KB.
// ---------------------------------------------------------------------------
__global__ __launch_bounds__(1024) void voxlin_lds(
    const float* __restrict__ X,
    const _Float16* __restrict__ Wp,
    const int* __restrict__ row_ids,
    const int* __restrict__ voxel_ids,
    float* __restrict__ out)
{
    __shared__ float4    lwv[HALF_F4];                // 102400 B table
    __shared__ float4    pts[1024];                   // 16 KB slots
    __shared__ int       wcnt[16];
    _Float16* const lw = (_Float16*)lwv;

    const int t    = threadIdx.x;
    const int lane = t & 63;
    const int wid  = t >> 6;
    const int i    = blockIdx.x * 1024 + t;

    // ---- issue half-0 DMA first: latency hides under partition+posenc ----
    stage_async(Wp, lw, t);

    const int   v  = voxel_ids[i];
    const float x0 = X[3*i + 0];
    const float x1 = X[3*i + 1];
    const float x2 = X[3*i + 2];
    const int   r  = row_ids[i];          // stays in this thread's registers

    // ---- 2-way partition by voxel half (ballot + popc, no atomics) ----
    const bool lo = (v < HALF_VOX);
    const unsigned long long m = __ballot(lo);
    if (lane == 0) wcnt[wid] = __popcll(m);
    __syncthreads();                                           // P1
    int pref_lo = 0, tot_lo = 0;
    #pragma unroll
    for (int w = 0; w < 16; ++w) {        // broadcast reads, all lanes same
        const int c = wcnt[w];
        if (w < wid) pref_lo += c;
        tot_lo += c;
    }
    const int mb = __popcll(m & ((1ull << lane) - 1ull));
    const int mypos = lo ? (pref_lo + mb)
                         : (tot_lo + 64 * wid - pref_lo + (lane - mb));
    pts[mypos] = make_float4(x0, x1, x2, __int_as_float(v));
    const int n0 = tot_lo;                // block-uniform
    __syncthreads();                                           // P2 (+DMA drain)

    // ---- compute for the point sitting at slot t ----
    const float4 q  = pts[t];
    const int    sv = __float_as_int(q.w);

    // posenc once (double-angle recurrence), packed to half2
    half2v eh[32];
    eh[0] = pkrtz(q.x, q.y);
    eh[1] = pkrtz(q.z, 0.0f);             // pairs with zero pad col 3
    {
        float s0, c0, s1, c1, s2, c2;
        __sincosf(q.x, &s0, &c0);
        __sincosf(q.y, &s1, &c1);
        __sincosf(q.z, &s2, &c2);
        #pragma unroll
        for (int f = 0; f < NUM_FREQS; ++f) {
            const int b = 2 + 3 * f;      // [s0 s1 | s2 c0 | c1 c2]
            eh[b + 0] = pkrtz(s0, s1);
            eh[b + 1] = pkrtz(s2, c0);
            eh[b + 2] = pkrtz(c1, c2);
            if (f < NUM_FREQS - 1) {
                const float ns0 = 2.0f*s0*c0, nc0 = c0*c0 - s0*s0;
                const float ns1 = 2.0f*s1*c1, nc1 = c1*c1 - s1*s1;
                const float ns2 = 2.0f*s2*c2, nc2 = c2*c2 - s2*s2;
                s0 = ns0; c0 = nc0; s1 = ns1; c1 = nc1; s2 = ns2; c2 = nc2;
            }
        }
    }

    float a0 = 0.0f, a1 = 0.0f, a2 = 0.0f;

    #pragma unroll
    for (int h = 0; h < 2; ++h) {
        if (h == 1) {
            __syncthreads();              // all half0 compute done            C1
            stage_async(Wp + HALF_HALFS, lw, t);
            __syncthreads();              // DMA drained -> table ready       C2
        }
        // slots are partitioned: phase h touches a contiguous range, so
        // waves are fully active / fully skipped (execz) except one boundary
        const bool active = (h == 0) ? (t < n0) : (t >= n0);
        if (active) {
            const uint4* __restrict__ wb =
                (const uint4*)lw + (sv & (HALF_VOX - 1)) * (VSTRIDE / 8);
            float acc[3];
            #pragma unroll
            for (int rr = 0; rr < 3; ++rr) {
                float a = 0.0f;
                #pragma unroll
                for (int k = 0; k < 8; ++k) {
                    const uint4 qq = wb[rr * 8 + k];
                    a = dot2acc(u2h(qq.x), eh[4*k + 0], a);
                    a = dot2acc(u2h(qq.y), eh[4*k + 1], a);
                    a = dot2acc(u2h(qq.z), eh[4*k + 2], a);
                    a = dot2acc(u2h(qq.w), eh[4*k + 3], a);
                }
                acc[rr] = a;
            }
            a0 = acc[0]; a1 = acc[1]; a2 = acc[2];
        }
    }

    // ---- unpermute: slot t's result -> pts; fetch own point's result ----
    __syncthreads();                                           // F0
    pts[t] = make_float4(a0, a1, a2, 0.0f);
    __syncthreads();                                           // F1
    const float4 res = pts[mypos];
    out[3*r + 0] = res.x;
    out[3*r + 1] = res.y;
    out[3*r + 2] = res.z;
}

// ---------------------------------------------------------------------------
// Fallback (R1 kernel) if ws too small for the 200 KB packed image.
// ---------------------------------------------------------------------------
__global__ __launch_bounds__(256) void voxlin_fallback(
    const float* __restrict__ X, const float* __restrict__ W,
    const int* __restrict__ row_ids, const int* __restrict__ voxel_ids,
    float* __restrict__ out)
{
    const int i = blockIdx.x * 256 + threadIdx.x;
    if (i >= N_POINTS) return;
    const float x0 = X[3*i], x1 = X[3*i+1], x2 = X[3*i+2];
    const int v = voxel_ids[i];
    const float* __restrict__ w0 = W + v * 189;
    const float* __restrict__ w1 = w0 + 63;
    const float* __restrict__ w2 = w0 + 126;
    float a0 = x0*w0[0] + x1*w0[1] + x2*w0[2];
    float a1 = x0*w1[0] + x1*w1[1] + x2*w1[2];
    float a2 = x0*w2[0] + x1*w2[1] + x2*w2[2];
    float s0, c0, s1, c1, s2, c2;
    __sincosf(x0, &s0, &c0); __sincosf(x1, &s1, &c1); __sincosf(x2, &s2, &c2);
    #pragma unroll
    for (int f = 0; f < NUM_FREQS; ++f) {
        const int b = 3 + 6*f;
        a0 += s0*w0[b] + s1*w0[b+1] + s2*w0[b+2] + c0*w0[b+3] + c1*w0[b+4] + c2*w0[b+5];
        a1 += s0*w1[b] + s1*w1[b+1] + s2*w1[b+2] + c0*w1[b+3] + c1*w1[b+4] + c2*w1[b+5];
        a2 += s0*w2[b] + s1*w2[b+1] + s2*w2[b+2] + c0*w2[b+3] + c1*w2[b+4] + c2*w2[b+5];
        if (f < NUM_FREQS - 1) {
            const float ns0 = 2.0f*s0*c0, nc0 = c0*c0 - s0*s0;
            const float ns1 = 2.0f*s1*c1, nc1 = c1*c1 - s1*s1;
            const float ns2 = 2.0f*s2*c2, nc2 = c2*c2 - s2*s2;
            s0 = ns0; c0 = nc0; s1 = ns1; c1 = nc1; s2 = ns2; c2 = nc2;
        }
    }
    const int rr = row_ids[i];
    out[3*rr] = a0; out[3*rr+1] = a1; out[3*rr+2] = a2;
}

// ---------------------------------------------------------------------------
extern "C" void kernel_launch(void* const* d_in, const int* in_sizes, int n_in,
                              void* d_out, int out_size, void* d_ws, size_t ws_size,
                              hipStream_t stream) {
    const float* X         = (const float*)d_in[0];
    const float* W         = (const float*)d_in[1];
    const int*   row_ids   = (const int*)d_in[2];
    const int*   voxel_ids = (const int*)d_in[3];
    float*       out       = (float*)d_out;

    const size_t need = (size_t)2 * HALF_HALFS * sizeof(_Float16); // 204800 B

    if (ws_size >= need) {
        _Float16* Wp = (_Float16*)d_ws;
        pack_w<<<100, 256, 0, stream>>>(W, Wp);
        voxlin_lds<<<N_POINTS / 1024, 1024, 0, stream>>>(X, Wp, row_ids,
                                                         voxel_ids, out);
    } else {
        voxlin_fallback<<<(N_POINTS + 255) / 256, 256, 0, stream>>>(
            X, W, row_ids, voxel_ids, out);
    }
}